// Round 1
// baseline (1336.626 us; speedup 1.0000x reference)
//
#include <hip/hip_runtime.h>

constexpr int N_NODES = 100000;
constexpr int DIM     = 128;
constexpr int N_EDGES = 640000;

// ---------------------------------------------------------------------------
// Scatter: agg[dst] += x[src]  (32 lanes per edge, float4 gather + 4 atomics)
//          deg[dst] += 1.0     (lane 0)
// ---------------------------------------------------------------------------
__global__ __launch_bounds__(256) void gcn_scatter(
    const float* __restrict__ x,
    const int*   __restrict__ src,
    const int*   __restrict__ dst,
    float*       __restrict__ agg,
    float*       __restrict__ deg)
{
    long gid = (long)blockIdx.x * blockDim.x + threadIdx.x;
    int  e   = (int)(gid >> 5);          // 32 threads per edge
    if (e >= N_EDGES) return;
    int lane = (int)(gid & 31);

    int s = src[e];
    int d = dst[e];

    const float4 v = *reinterpret_cast<const float4*>(x + (size_t)s * DIM + lane * 4);
    float* a = agg + (size_t)d * DIM + lane * 4;
    atomicAdd(a + 0, v.x);
    atomicAdd(a + 1, v.y);
    atomicAdd(a + 2, v.z);
    atomicAdd(a + 3, v.w);
    if (lane == 0) atomicAdd(deg + d, 1.0f);
}

// ---------------------------------------------------------------------------
// Fused: h = agg/max(deg,1) + x ; out = relu(h @ W^T + b)
// Block = 128 threads (thread j owns output feature j), NB=8 nodes staged per
// iteration so every W LDS read is reused 8x. W in LDS [128][132] (pad=+4
// floats keeps float4 rows 16B-aligned and spreads banks evenly).
// ---------------------------------------------------------------------------
constexpr int NB = 8;

__global__ __launch_bounds__(128) void gcn_gemm(
    const float* __restrict__ x,
    const float* __restrict__ agg,
    const float* __restrict__ deg,
    const float* __restrict__ W,
    const float* __restrict__ bias,
    float*       __restrict__ out)
{
    __shared__ float Wl[DIM][DIM + 4];
    __shared__ float hl[NB][DIM];

    const int tid = threadIdx.x;   // 0..127 == output feature j

    // Cooperative W load: 16384 floats via float4 (32 iters of 128 threads)
    for (int i = tid; i < DIM * DIM / 4; i += 128) {
        float4 w4 = reinterpret_cast<const float4*>(W)[i];
        int j = (i * 4) >> 7;
        int k = (i * 4) & (DIM - 1);
        *reinterpret_cast<float4*>(&Wl[j][k]) = w4;
    }
    const float bj = bias[tid];

    const int chunk = (N_NODES + gridDim.x - 1) / gridDim.x;
    const int nbeg  = blockIdx.x * chunk;
    const int nend  = min(nbeg + chunk, N_NODES);

    for (int n0 = nbeg; n0 < nend; n0 += NB) {
        __syncthreads();   // covers W load on first iter + hl reuse after
        // Stage h for NB nodes: 1024 floats / 128 threads = 8 each, coalesced
        for (int i = tid; i < NB * DIM; i += 128) {
            int ln = i >> 7;
            int k  = i & (DIM - 1);
            int n  = n0 + ln;
            if (n < nend) {
                float inv = 1.0f / fmaxf(deg[n], 1.0f);
                hl[ln][k] = agg[(size_t)n * DIM + k] * inv + x[(size_t)n * DIM + k];
            }
        }
        __syncthreads();

        float acc[NB];
        #pragma unroll
        for (int ln = 0; ln < NB; ++ln) acc[ln] = bj;

        #pragma unroll 4
        for (int k = 0; k < DIM; k += 4) {
            float4 w4 = *reinterpret_cast<const float4*>(&Wl[tid][k]);
            #pragma unroll
            for (int ln = 0; ln < NB; ++ln) {
                float4 h4 = *reinterpret_cast<const float4*>(&hl[ln][k]); // broadcast
                acc[ln] += w4.x * h4.x + w4.y * h4.y + w4.z * h4.z + w4.w * h4.w;
            }
        }

        #pragma unroll
        for (int ln = 0; ln < NB; ++ln) {
            int n = n0 + ln;
            if (n < nend)
                out[(size_t)n * DIM + tid] = fmaxf(acc[ln], 0.0f);
        }
    }
}

extern "C" void kernel_launch(void* const* d_in, const int* in_sizes, int n_in,
                              void* d_out, int out_size, void* d_ws, size_t ws_size,
                              hipStream_t stream)
{
    const float* x    = (const float*)d_in[0];
    const int*   eidx = (const int*)d_in[1];   // [2, E] flat: src then dst
    const float* W    = (const float*)d_in[2];
    const float* bias = (const float*)d_in[3];
    float*       out  = (float*)d_out;

    const int* src = eidx;
    const int* dst = eidx + N_EDGES;

    float* agg = (float*)d_ws;                       // N_NODES * DIM
    float* deg = agg + (size_t)N_NODES * DIM;        // N_NODES

    size_t zero_bytes = ((size_t)N_NODES * DIM + N_NODES) * sizeof(float);
    hipMemsetAsync(d_ws, 0, zero_bytes, stream);

    {
        long threads = (long)N_EDGES * 32;
        int  blocks  = (int)((threads + 255) / 256);
        gcn_scatter<<<blocks, 256, 0, stream>>>(x, src, dst, agg, deg);
    }
    {
        int blocks = 2500;  // chunk = 40 nodes/block; 2 resident blocks/CU (66KB LDS)
        gcn_gemm<<<blocks, 128, 0, stream>>>(x, agg, deg, W, bias, out);
    }
}

// Round 2
// 272.083 us; speedup vs baseline: 4.9126x; 4.9126x over previous
//
#include <hip/hip_runtime.h>

constexpr int N_NODES = 100000;
constexpr int DIM     = 128;
constexpr int N_EDGES = 640000;

constexpr int SCAN_CHUNK  = 1024;
constexpr int N_CHUNKS    = (N_NODES + SCAN_CHUNK - 1) / SCAN_CHUNK;   // 98
constexpr int WS_STRIDE   = 100352;                                    // ints, >=N_NODES+1

// ---------------------------------------------------------------------------
// 1) Histogram of dst -> cnt[n]
// ---------------------------------------------------------------------------
__global__ __launch_bounds__(256) void gcn_hist(const int* __restrict__ dst,
                                                int* __restrict__ cnt)
{
    int e = blockIdx.x * 256 + threadIdx.x;
    if (e < N_EDGES) atomicAdd(&cnt[dst[e]], 1);
}

// ---------------------------------------------------------------------------
// 2) Exclusive scan of cnt -> off, per-1024 chunk; chunk totals -> bsum
// ---------------------------------------------------------------------------
__global__ __launch_bounds__(256) void gcn_scan1(const int* __restrict__ cnt,
                                                 int* __restrict__ off,
                                                 int* __restrict__ bsum)
{
    __shared__ int s[256];
    const int t    = threadIdx.x;
    const int base = blockIdx.x * SCAN_CHUNK + t * 4;

    int v0 = (base + 0 < N_NODES) ? cnt[base + 0] : 0;
    int v1 = (base + 1 < N_NODES) ? cnt[base + 1] : 0;
    int v2 = (base + 2 < N_NODES) ? cnt[base + 2] : 0;
    int v3 = (base + 3 < N_NODES) ? cnt[base + 3] : 0;

    int local = v0 + v1 + v2 + v3;
    s[t] = local;
    __syncthreads();
    // Hillis-Steele inclusive scan over 256 thread sums
    for (int d = 1; d < 256; d <<= 1) {
        int add = (t >= d) ? s[t - d] : 0;
        __syncthreads();
        s[t] += add;
        __syncthreads();
    }
    int excl = (t > 0) ? s[t - 1] : 0;

    if (base + 0 < N_NODES) off[base + 0] = excl;
    if (base + 1 < N_NODES) off[base + 1] = excl + v0;
    if (base + 2 < N_NODES) off[base + 2] = excl + v0 + v1;
    if (base + 3 < N_NODES) off[base + 3] = excl + v0 + v1 + v2;
    if (t == 255) bsum[blockIdx.x] = s[255];
}

// 2b) Exclusive scan of the 98 chunk totals (single block)
__global__ __launch_bounds__(128) void gcn_scan2(int* __restrict__ bsum)
{
    __shared__ int s[128];
    const int t = threadIdx.x;
    s[t] = (t < N_CHUNKS) ? bsum[t] : 0;
    __syncthreads();
    for (int d = 1; d < 128; d <<= 1) {
        int add = (t >= d) ? s[t - d] : 0;
        __syncthreads();
        s[t] += add;
        __syncthreads();
    }
    if (t < N_CHUNKS) bsum[t] = (t > 0) ? s[t - 1] : 0;
}

// 2c) Add chunk offsets; mirror into cursor array; set off[N] = E
__global__ __launch_bounds__(256) void gcn_scan3(int* __restrict__ off,
                                                 int* __restrict__ cur,
                                                 const int* __restrict__ bsum)
{
    const int t    = threadIdx.x;
    const int base = blockIdx.x * SCAN_CHUNK + t * 4;
    const int add  = bsum[blockIdx.x];
    #pragma unroll
    for (int q = 0; q < 4; ++q) {
        int idx = base + q;
        if (idx < N_NODES) {
            int v = off[idx] + add;
            off[idx] = v;
            cur[idx] = v;
        }
    }
    if (blockIdx.x == 0 && t == 0) off[N_NODES] = N_EDGES;
}

// ---------------------------------------------------------------------------
// 3) Fill CSR: csr[slot(dst)] = src
// ---------------------------------------------------------------------------
__global__ __launch_bounds__(256) void gcn_fill(const int* __restrict__ src,
                                                const int* __restrict__ dst,
                                                int* __restrict__ cur,
                                                int* __restrict__ csr)
{
    int e = blockIdx.x * 256 + threadIdx.x;
    if (e < N_EDGES) {
        int d = dst[e];
        int p = atomicAdd(&cur[d], 1);
        csr[p] = src[e];
    }
}

// ---------------------------------------------------------------------------
// 4) Gather-aggregate: h[n] = (sum_{s in csr[n]} x[s]) / max(deg,1) + x[n]
//    32 lanes per node, float4 per lane. h written to hbuf (= d_out).
// ---------------------------------------------------------------------------
__global__ __launch_bounds__(256) void gcn_gather(const float* __restrict__ x,
                                                  const int* __restrict__ off,
                                                  const int* __restrict__ csr,
                                                  float* __restrict__ hbuf)
{
    const int tid  = threadIdx.x;
    const int g    = tid >> 5;          // node group 0..7
    const int lane = tid & 31;
    const int n    = blockIdx.x * 8 + g;    // grid sized exactly: n < N_NODES

    const int start = off[n];
    const int end   = off[n + 1];

    float4 acc = make_float4(0.f, 0.f, 0.f, 0.f);
    int s = (start < end) ? csr[start] : 0;
    for (int i = start; i < end; ++i) {
        int snext = (i + 1 < end) ? csr[i + 1] : 0;   // prefetch index
        const float4 v = *reinterpret_cast<const float4*>(
            x + (size_t)s * DIM + lane * 4);
        acc.x += v.x; acc.y += v.y; acc.z += v.z; acc.w += v.w;
        s = snext;
    }
    const float inv = 1.0f / fmaxf((float)(end - start), 1.0f);
    const float4 xr = *reinterpret_cast<const float4*>(
        x + (size_t)n * DIM + lane * 4);
    float4 h;
    h.x = acc.x * inv + xr.x;
    h.y = acc.y * inv + xr.y;
    h.z = acc.z * inv + xr.z;
    h.w = acc.w * inv + xr.w;
    *reinterpret_cast<float4*>(hbuf + (size_t)n * DIM + lane * 4) = h;
}

// ---------------------------------------------------------------------------
// 5) GEMM: out = relu(h @ W^T + b), in-place over hbuf (stage rows to LDS,
//    barrier, then overwrite). W row lives in 32 float4 registers per thread.
//    256 threads: j = tid&127 (output feature), half = tid>>7 owns 8 nodes.
// ---------------------------------------------------------------------------
constexpr int GNB = 16;   // nodes per block

__global__ __launch_bounds__(256) void gcn_gemm(const float* __restrict__ W,
                                                const float* __restrict__ bias,
                                                float* __restrict__ hio)
{
    __shared__ float hl[GNB][DIM];

    const int tid  = threadIdx.x;
    const int j    = tid & 127;
    const int half = tid >> 7;
    const int n0   = blockIdx.x * GNB;

    // W row j -> 32 float4 registers (static indices, fully unrolled)
    float4 w[32];
    #pragma unroll
    for (int k4 = 0; k4 < 32; ++k4)
        w[k4] = *reinterpret_cast<const float4*>(W + (size_t)j * DIM + k4 * 4);
    const float bj = bias[j];

    // Stage GNB h rows: 512 float4 / 256 threads = 2 each, coalesced
    {
        const float4* hsrc = reinterpret_cast<const float4*>(hio + (size_t)n0 * DIM);
        float4* hdst = reinterpret_cast<float4*>(&hl[0][0]);
        hdst[tid]       = hsrc[tid];
        hdst[tid + 256] = hsrc[tid + 256];
    }
    __syncthreads();

    float acc[8];
    #pragma unroll
    for (int ln = 0; ln < 8; ++ln) acc[ln] = bj;

    #pragma unroll
    for (int k4 = 0; k4 < 32; ++k4) {
        const float4 w4 = w[k4];
        #pragma unroll
        for (int ln = 0; ln < 8; ++ln) {
            const float4 h4 = *reinterpret_cast<const float4*>(
                &hl[half * 8 + ln][k4 * 4]);   // wave-uniform -> LDS broadcast
            acc[ln] += w4.x * h4.x + w4.y * h4.y + w4.z * h4.z + w4.w * h4.w;
        }
    }

    #pragma unroll
    for (int ln = 0; ln < 8; ++ln) {
        const int n = n0 + half * 8 + ln;
        hio[(size_t)n * DIM + j] = fmaxf(acc[ln], 0.0f);
    }
}

// ---------------------------------------------------------------------------
extern "C" void kernel_launch(void* const* d_in, const int* in_sizes, int n_in,
                              void* d_out, int out_size, void* d_ws, size_t ws_size,
                              hipStream_t stream)
{
    const float* x    = (const float*)d_in[0];
    const int*   eidx = (const int*)d_in[1];   // [2, E] flat: src row then dst row
    const float* W    = (const float*)d_in[2];
    const float* bias = (const float*)d_in[3];
    float*       out  = (float*)d_out;         // doubles as h buffer

    const int* src = eidx;
    const int* dst = eidx + N_EDGES;

    int* cnt  = (int*)d_ws;                 // [N]
    int* off  = cnt  + WS_STRIDE;           // [N+1]
    int* cur  = off  + WS_STRIDE;           // [N]
    int* bsum = cur  + WS_STRIDE;           // [N_CHUNKS]
    int* csr  = bsum + 512;                 // [E]

    hipMemsetAsync(cnt, 0, (size_t)N_NODES * sizeof(int), stream);

    gcn_hist <<<(N_EDGES + 255) / 256, 256, 0, stream>>>(dst, cnt);
    gcn_scan1<<<N_CHUNKS, 256, 0, stream>>>(cnt, off, bsum);
    gcn_scan2<<<1, 128, 0, stream>>>(bsum);
    gcn_scan3<<<N_CHUNKS, 256, 0, stream>>>(off, cur, bsum);
    gcn_fill <<<(N_EDGES + 255) / 256, 256, 0, stream>>>(src, dst, cur, csr);
    gcn_gather<<<N_NODES / 8, 256, 0, stream>>>(x, off, csr, out);
    gcn_gemm <<<N_NODES / GNB, 256, 0, stream>>>(W, bias, out);
}

// Round 3
// 177.797 us; speedup vs baseline: 7.5177x; 1.5303x over previous
//
#include <hip/hip_runtime.h>
#include <hip/hip_bf16.h>

constexpr int N_NODES = 100000;
constexpr int DIM     = 128;
constexpr int N_EDGES = 640000;

constexpr int SCAN_CHUNK  = 1024;
constexpr int N_CHUNKS    = (N_NODES + SCAN_CHUNK - 1) / SCAN_CHUNK;   // 98
constexpr int WS_STRIDE   = 100352;                                    // ints

typedef __attribute__((ext_vector_type(4))) float f32x4;
typedef __attribute__((ext_vector_type(8))) short bf16x8;

static __device__ inline unsigned short f2bf(float f) {
    __hip_bfloat16 h = __float2bfloat16(f);   // RNE
    return *reinterpret_cast<unsigned short*>(&h);
}

// ---------------------------------------------------------------------------
// 1) Histogram of dst -> cnt[n]
// ---------------------------------------------------------------------------
__global__ __launch_bounds__(256) void gcn_hist(const int* __restrict__ dst,
                                                int* __restrict__ cnt)
{
    int e = blockIdx.x * 256 + threadIdx.x;
    if (e < N_EDGES) atomicAdd(&cnt[dst[e]], 1);
}

// ---------------------------------------------------------------------------
// 2) Exclusive scan of cnt -> off (3 kernels)
// ---------------------------------------------------------------------------
__global__ __launch_bounds__(256) void gcn_scan1(const int* __restrict__ cnt,
                                                 int* __restrict__ off,
                                                 int* __restrict__ bsum)
{
    __shared__ int s[256];
    const int t    = threadIdx.x;
    const int base = blockIdx.x * SCAN_CHUNK + t * 4;

    int v0 = (base + 0 < N_NODES) ? cnt[base + 0] : 0;
    int v1 = (base + 1 < N_NODES) ? cnt[base + 1] : 0;
    int v2 = (base + 2 < N_NODES) ? cnt[base + 2] : 0;
    int v3 = (base + 3 < N_NODES) ? cnt[base + 3] : 0;

    s[t] = v0 + v1 + v2 + v3;
    __syncthreads();
    for (int d = 1; d < 256; d <<= 1) {
        int add = (t >= d) ? s[t - d] : 0;
        __syncthreads();
        s[t] += add;
        __syncthreads();
    }
    int excl = (t > 0) ? s[t - 1] : 0;

    if (base + 0 < N_NODES) off[base + 0] = excl;
    if (base + 1 < N_NODES) off[base + 1] = excl + v0;
    if (base + 2 < N_NODES) off[base + 2] = excl + v0 + v1;
    if (base + 3 < N_NODES) off[base + 3] = excl + v0 + v1 + v2;
    if (t == 255) bsum[blockIdx.x] = s[255];
}

__global__ __launch_bounds__(128) void gcn_scan2(int* __restrict__ bsum)
{
    __shared__ int s[128];
    const int t = threadIdx.x;
    s[t] = (t < N_CHUNKS) ? bsum[t] : 0;
    __syncthreads();
    for (int d = 1; d < 128; d <<= 1) {
        int add = (t >= d) ? s[t - d] : 0;
        __syncthreads();
        s[t] += add;
        __syncthreads();
    }
    if (t < N_CHUNKS) bsum[t] = (t > 0) ? s[t - 1] : 0;
}

__global__ __launch_bounds__(256) void gcn_scan3(int* __restrict__ off,
                                                 int* __restrict__ cur,
                                                 const int* __restrict__ bsum)
{
    const int t    = threadIdx.x;
    const int base = blockIdx.x * SCAN_CHUNK + t * 4;
    const int add  = bsum[blockIdx.x];
    #pragma unroll
    for (int q = 0; q < 4; ++q) {
        int idx = base + q;
        if (idx < N_NODES) {
            int v = off[idx] + add;
            off[idx] = v;
            cur[idx] = v;
        }
    }
    if (blockIdx.x == 0 && t == 0) off[N_NODES] = N_EDGES;
}

// ---------------------------------------------------------------------------
// 3) Fill CSR: csr[slot(dst)] = src
// ---------------------------------------------------------------------------
__global__ __launch_bounds__(256) void gcn_fill(const int* __restrict__ src,
                                                const int* __restrict__ dst,
                                                int* __restrict__ cur,
                                                int* __restrict__ csr)
{
    int e = blockIdx.x * 256 + threadIdx.x;
    if (e < N_EDGES) {
        int d = dst[e];
        int p = atomicAdd(&cur[d], 1);
        csr[p] = src[e];
    }
}

// ---------------------------------------------------------------------------
// 4) W -> bf16 (once): 16384 elements
// ---------------------------------------------------------------------------
__global__ __launch_bounds__(256) void gcn_wconv(const float* __restrict__ W,
                                                 unsigned short* __restrict__ wb)
{
    int i = blockIdx.x * 256 + threadIdx.x;   // grid = 64 blocks -> exactly 16384
    wb[i] = f2bf(W[i]);
}

// ---------------------------------------------------------------------------
// 5) Gather-aggregate -> h in bf16: h[n] = sum(x[src])/max(deg,1) + x[n]
//    32 lanes per node, float4 per lane; bf16 ushort4 (8B) store.
// ---------------------------------------------------------------------------
__global__ __launch_bounds__(256) void gcn_gather(const float* __restrict__ x,
                                                  const int* __restrict__ off,
                                                  const int* __restrict__ csr,
                                                  unsigned short* __restrict__ hb)
{
    const int tid  = threadIdx.x;
    const int g    = tid >> 5;
    const int lane = tid & 31;
    const int n    = blockIdx.x * 8 + g;    // grid sized exactly

    const int start = off[n];
    const int end   = off[n + 1];

    float4 acc = make_float4(0.f, 0.f, 0.f, 0.f);
    int s = (start < end) ? csr[start] : 0;
    for (int i = start; i < end; ++i) {
        int snext = (i + 1 < end) ? csr[i + 1] : 0;
        const float4 v = *reinterpret_cast<const float4*>(
            x + (size_t)s * DIM + lane * 4);
        acc.x += v.x; acc.y += v.y; acc.z += v.z; acc.w += v.w;
        s = snext;
    }
    const float inv = 1.0f / fmaxf((float)(end - start), 1.0f);
    const float4 xr = *reinterpret_cast<const float4*>(
        x + (size_t)n * DIM + lane * 4);

    ushort4 o;
    o.x = f2bf(acc.x * inv + xr.x);
    o.y = f2bf(acc.y * inv + xr.y);
    o.z = f2bf(acc.z * inv + xr.z);
    o.w = f2bf(acc.w * inv + xr.w);
    *reinterpret_cast<ushort4*>(hb + (size_t)n * DIM + lane * 4) = o;
}

// ---------------------------------------------------------------------------
// 6) MFMA GEMM: out = relu(h @ W^T + b)
//    Wave = 16 nodes x 128 features. W-frags resident in 128 VGPRs.
//    mfma_f32_16x16x32_bf16: A lane(r=l&15,g=l>>4) holds A[r][8g+0..7];
//    B lane holds B[8g+0..7][c=l&15]  (= W[c][8g+0..7], contiguous row-load);
//    D lane: col=l&15, row=4g+q (m89-verified).
// ---------------------------------------------------------------------------
constexpr int N_TILES = N_NODES / 16;   // 6250

__global__ __launch_bounds__(256) void gcn_mfma(
    const short* __restrict__ hb,
    const short* __restrict__ wb,
    const float* __restrict__ bias,
    float* __restrict__ out)
{
    const int wid  = threadIdx.x >> 6;
    const int lane = threadIdx.x & 63;
    const int tile = blockIdx.x * 4 + wid;
    if (tile >= N_TILES) return;
    const int row0 = tile * 16;

    const int r = lane & 15;
    const int g = lane >> 4;

    // B-frags: all of W, resident
    bf16x8 wf[8][4];
    #pragma unroll
    for (int c = 0; c < 8; ++c)
        #pragma unroll
        for (int t = 0; t < 4; ++t)
            wf[c][t] = *reinterpret_cast<const bf16x8*>(
                wb + (16 * c + r) * DIM + 32 * t + 8 * g);

    // A-frags: 16 h rows
    bf16x8 af[4];
    #pragma unroll
    for (int t = 0; t < 4; ++t)
        af[t] = *reinterpret_cast<const bf16x8*>(
            hb + (size_t)(row0 + r) * DIM + 32 * t + 8 * g);

    f32x4 acc[8];
    #pragma unroll
    for (int c = 0; c < 8; ++c) acc[c] = {0.f, 0.f, 0.f, 0.f};

    #pragma unroll
    for (int t = 0; t < 4; ++t)
        #pragma unroll
        for (int c = 0; c < 8; ++c)
            acc[c] = __builtin_amdgcn_mfma_f32_16x16x32_bf16(af[t], wf[c][t], acc[c], 0, 0, 0);

    #pragma unroll
    for (int c = 0; c < 8; ++c) {
        const float bj = bias[16 * c + r];
        #pragma unroll
        for (int q = 0; q < 4; ++q)
            out[(size_t)(row0 + 4 * g + q) * DIM + 16 * c + r] =
                fmaxf(acc[c][q] + bj, 0.0f);
    }
}

// ---------------------------------------------------------------------------
extern "C" void kernel_launch(void* const* d_in, const int* in_sizes, int n_in,
                              void* d_out, int out_size, void* d_ws, size_t ws_size,
                              hipStream_t stream)
{
    const float* x    = (const float*)d_in[0];
    const int*   eidx = (const int*)d_in[1];
    const float* W    = (const float*)d_in[2];
    const float* bias = (const float*)d_in[3];
    float*       out  = (float*)d_out;

    const int* src = eidx;
    const int* dst = eidx + N_EDGES;

    int* cnt  = (int*)d_ws;                         // [N]
    int* off  = cnt  + WS_STRIDE;                   // [N+1]
    int* cur  = off  + WS_STRIDE;                   // [N]
    int* bsum = cur  + WS_STRIDE;                   // [512]
    int* csr  = bsum + 512;                         // [E]
    unsigned short* wb = (unsigned short*)(csr + N_EDGES);          // [128*128]
    unsigned short* hb = wb + (size_t)DIM * DIM;                    // [N*128] bf16

    hipMemsetAsync(cnt, 0, (size_t)N_NODES * sizeof(int), stream);

    gcn_hist <<<(N_EDGES + 255) / 256, 256, 0, stream>>>(dst, cnt);
    gcn_scan1<<<N_CHUNKS, 256, 0, stream>>>(cnt, off, bsum);
    gcn_scan2<<<1, 128, 0, stream>>>(bsum);
    gcn_scan3<<<N_CHUNKS, 256, 0, stream>>>(off, cur, bsum);
    gcn_fill <<<(N_EDGES + 255) / 256, 256, 0, stream>>>(src, dst, cur, csr);
    gcn_wconv<<<DIM * DIM / 256, 256, 0, stream>>>(W, wb);
    gcn_gather<<<N_NODES / 8, 256, 0, stream>>>(x, off, csr, hb);
    gcn_mfma <<<(N_TILES + 3) / 4, 256, 0, stream>>>(
        (const short*)hb, (const short*)wb, bias, out);
}

// Round 4
// 161.420 us; speedup vs baseline: 8.2804x; 1.1015x over previous
//
#include <hip/hip_runtime.h>
#include <hip/hip_bf16.h>

constexpr int N_NODES = 100000;
constexpr int DIM     = 128;
constexpr int N_EDGES = 640000;

constexpr int SCAN_CHUNK  = 1024;
constexpr int N_CHUNKS    = (N_NODES + SCAN_CHUNK - 1) / SCAN_CHUNK;   // 98
constexpr int WS_STRIDE   = 100352;                                    // ints

typedef __attribute__((ext_vector_type(4))) float        f32x4;
typedef __attribute__((ext_vector_type(8))) short        bf16x8;
typedef __attribute__((ext_vector_type(4))) unsigned int u32x4;

static __device__ inline unsigned short f2bf(float f) {
    __hip_bfloat16 h = __float2bfloat16(f);   // RNE
    return *reinterpret_cast<unsigned short*>(&h);
}
static __device__ inline float bf_lo(unsigned u) { return __uint_as_float(u << 16); }
static __device__ inline float bf_hi(unsigned u) { return __uint_as_float(u & 0xffff0000u); }

// ---------------------------------------------------------------------------
// 1) Histogram of dst -> cnt[n]
// ---------------------------------------------------------------------------
__global__ __launch_bounds__(256) void gcn_hist(const int* __restrict__ dst,
                                                int* __restrict__ cnt)
{
    int e = blockIdx.x * 256 + threadIdx.x;
    if (e < N_EDGES) atomicAdd(&cnt[dst[e]], 1);
}

// ---------------------------------------------------------------------------
// 2) Exclusive scan of cnt -> off (3 kernels)
// ---------------------------------------------------------------------------
__global__ __launch_bounds__(256) void gcn_scan1(const int* __restrict__ cnt,
                                                 int* __restrict__ off,
                                                 int* __restrict__ bsum)
{
    __shared__ int s[256];
    const int t    = threadIdx.x;
    const int base = blockIdx.x * SCAN_CHUNK + t * 4;

    int v0 = (base + 0 < N_NODES) ? cnt[base + 0] : 0;
    int v1 = (base + 1 < N_NODES) ? cnt[base + 1] : 0;
    int v2 = (base + 2 < N_NODES) ? cnt[base + 2] : 0;
    int v3 = (base + 3 < N_NODES) ? cnt[base + 3] : 0;

    s[t] = v0 + v1 + v2 + v3;
    __syncthreads();
    for (int d = 1; d < 256; d <<= 1) {
        int add = (t >= d) ? s[t - d] : 0;
        __syncthreads();
        s[t] += add;
        __syncthreads();
    }
    int excl = (t > 0) ? s[t - 1] : 0;

    if (base + 0 < N_NODES) off[base + 0] = excl;
    if (base + 1 < N_NODES) off[base + 1] = excl + v0;
    if (base + 2 < N_NODES) off[base + 2] = excl + v0 + v1;
    if (base + 3 < N_NODES) off[base + 3] = excl + v0 + v1 + v2;
    if (t == 255) bsum[blockIdx.x] = s[255];
}

__global__ __launch_bounds__(128) void gcn_scan2(int* __restrict__ bsum)
{
    __shared__ int s[128];
    const int t = threadIdx.x;
    s[t] = (t < N_CHUNKS) ? bsum[t] : 0;
    __syncthreads();
    for (int d = 1; d < 128; d <<= 1) {
        int add = (t >= d) ? s[t - d] : 0;
        __syncthreads();
        s[t] += add;
        __syncthreads();
    }
    if (t < N_CHUNKS) bsum[t] = (t > 0) ? s[t - 1] : 0;
}

__global__ __launch_bounds__(256) void gcn_scan3(int* __restrict__ off,
                                                 int* __restrict__ cur,
                                                 const int* __restrict__ bsum)
{
    const int t    = threadIdx.x;
    const int base = blockIdx.x * SCAN_CHUNK + t * 4;
    const int add  = bsum[blockIdx.x];
    #pragma unroll
    for (int q = 0; q < 4; ++q) {
        int idx = base + q;
        if (idx < N_NODES) {
            int v = off[idx] + add;
            off[idx] = v;
            cur[idx] = v;
        }
    }
    if (blockIdx.x == 0 && t == 0) off[N_NODES] = N_EDGES;
}

// ---------------------------------------------------------------------------
// 3) Fill CSR: csr[slot(dst)] = src
// ---------------------------------------------------------------------------
__global__ __launch_bounds__(256) void gcn_fill(const int* __restrict__ src,
                                                const int* __restrict__ dst,
                                                int* __restrict__ cur,
                                                int* __restrict__ csr)
{
    int e = blockIdx.x * 256 + threadIdx.x;
    if (e < N_EDGES) {
        int d = dst[e];
        int p = atomicAdd(&cur[d], 1);
        csr[p] = src[e];
    }
}

// ---------------------------------------------------------------------------
// 4a) W -> bf16 (16384 elems)
// ---------------------------------------------------------------------------
__global__ __launch_bounds__(256) void gcn_wconv(const float* __restrict__ W,
                                                 unsigned short* __restrict__ wb)
{
    int i = blockIdx.x * 256 + threadIdx.x;   // 64 blocks -> exactly 16384
    wb[i] = f2bf(W[i]);
}

// 4b) x -> bf16 (12.8M elems, 8 per thread)
__global__ __launch_bounds__(256) void gcn_xconv(const float* __restrict__ x,
                                                 unsigned int* __restrict__ xb)
{
    int i = blockIdx.x * 256 + threadIdx.x;   // 6250 blocks -> exactly 1.6M
    const f32x4* src = reinterpret_cast<const f32x4*>(x);
    f32x4 a = src[2 * i];
    f32x4 b = src[2 * i + 1];
    u32x4 o;
    o.x = (unsigned)f2bf(a.x) | ((unsigned)f2bf(a.y) << 16);
    o.y = (unsigned)f2bf(a.z) | ((unsigned)f2bf(a.w) << 16);
    o.z = (unsigned)f2bf(b.x) | ((unsigned)f2bf(b.y) << 16);
    o.w = (unsigned)f2bf(b.z) | ((unsigned)f2bf(b.w) << 16);
    reinterpret_cast<u32x4*>(xb)[i] = o;
}

// ---------------------------------------------------------------------------
// 5) Gather-aggregate from bf16 x: h[n] = sum(xb[src])/max(deg,1) + xb[n]
//    16 lanes per node, 16B (8 bf16) per lane, 4-deep edge unroll for MLP.
// ---------------------------------------------------------------------------
static __device__ inline void acc8(float* acc, u32x4 v) {
    #pragma unroll
    for (int q = 0; q < 4; ++q) {
        unsigned u = v[q];
        acc[2 * q]     += bf_lo(u);
        acc[2 * q + 1] += bf_hi(u);
    }
}

__global__ __launch_bounds__(256) void gcn_gather(
    const unsigned short* __restrict__ xb,
    const int* __restrict__ off,
    const int* __restrict__ csr,
    unsigned int* __restrict__ hb)
{
    const int tid  = threadIdx.x;
    const int lane = tid & 15;                 // 8 dims per lane
    const int n    = blockIdx.x * 16 + (tid >> 4);   // grid exact

    const int start = off[n];
    const int end   = off[n + 1];
    const int col8  = lane * 8;

    float acc[8];
    #pragma unroll
    for (int q = 0; q < 8; ++q) acc[q] = 0.0f;

    int i = start;
    for (; i + 4 <= end; i += 4) {
        int s0 = csr[i], s1 = csr[i + 1], s2 = csr[i + 2], s3 = csr[i + 3];
        u32x4 v0 = *reinterpret_cast<const u32x4*>(xb + (size_t)s0 * DIM + col8);
        u32x4 v1 = *reinterpret_cast<const u32x4*>(xb + (size_t)s1 * DIM + col8);
        u32x4 v2 = *reinterpret_cast<const u32x4*>(xb + (size_t)s2 * DIM + col8);
        u32x4 v3 = *reinterpret_cast<const u32x4*>(xb + (size_t)s3 * DIM + col8);
        acc8(acc, v0); acc8(acc, v1); acc8(acc, v2); acc8(acc, v3);
    }
    for (; i < end; ++i) {
        int s = csr[i];
        u32x4 v = *reinterpret_cast<const u32x4*>(xb + (size_t)s * DIM + col8);
        acc8(acc, v);
    }

    const float inv = 1.0f / fmaxf((float)(end - start), 1.0f);
    const u32x4 xr = *reinterpret_cast<const u32x4*>(xb + (size_t)n * DIM + col8);

    u32x4 o;
    #pragma unroll
    for (int q = 0; q < 4; ++q) {
        float h0 = acc[2 * q]     * inv + bf_lo(xr[q]);
        float h1 = acc[2 * q + 1] * inv + bf_hi(xr[q]);
        o[q] = (unsigned)f2bf(h0) | ((unsigned)f2bf(h1) << 16);
    }
    reinterpret_cast<u32x4*>(hb)[(size_t)n * (DIM / 8) + lane] = o;
}

// ---------------------------------------------------------------------------
// 6) MFMA GEMM: out = relu(h @ W^T + b)   (unchanged from R3, verified)
// ---------------------------------------------------------------------------
constexpr int N_TILES = N_NODES / 16;   // 6250

__global__ __launch_bounds__(256) void gcn_mfma(
    const short* __restrict__ hb,
    const short* __restrict__ wb,
    const float* __restrict__ bias,
    float* __restrict__ out)
{
    const int wid  = threadIdx.x >> 6;
    const int lane = threadIdx.x & 63;
    const int tile = blockIdx.x * 4 + wid;
    if (tile >= N_TILES) return;
    const int row0 = tile * 16;

    const int r = lane & 15;
    const int g = lane >> 4;

    bf16x8 wf[8][4];
    #pragma unroll
    for (int c = 0; c < 8; ++c)
        #pragma unroll
        for (int t = 0; t < 4; ++t)
            wf[c][t] = *reinterpret_cast<const bf16x8*>(
                wb + (16 * c + r) * DIM + 32 * t + 8 * g);

    bf16x8 af[4];
    #pragma unroll
    for (int t = 0; t < 4; ++t)
        af[t] = *reinterpret_cast<const bf16x8*>(
            hb + (size_t)(row0 + r) * DIM + 32 * t + 8 * g);

    f32x4 acc[8];
    #pragma unroll
    for (int c = 0; c < 8; ++c) acc[c] = {0.f, 0.f, 0.f, 0.f};

    #pragma unroll
    for (int t = 0; t < 4; ++t)
        #pragma unroll
        for (int c = 0; c < 8; ++c)
            acc[c] = __builtin_amdgcn_mfma_f32_16x16x32_bf16(af[t], wf[c][t], acc[c], 0, 0, 0);

    #pragma unroll
    for (int c = 0; c < 8; ++c) {
        const float bj = bias[16 * c + r];
        #pragma unroll
        for (int q = 0; q < 4; ++q)
            out[(size_t)(row0 + 4 * g + q) * DIM + 16 * c + r] =
                fmaxf(acc[c][q] + bj, 0.0f);
    }
}

// ---------------------------------------------------------------------------
extern "C" void kernel_launch(void* const* d_in, const int* in_sizes, int n_in,
                              void* d_out, int out_size, void* d_ws, size_t ws_size,
                              hipStream_t stream)
{
    const float* x    = (const float*)d_in[0];
    const int*   eidx = (const int*)d_in[1];
    const float* W    = (const float*)d_in[2];
    const float* bias = (const float*)d_in[3];
    float*       out  = (float*)d_out;

    const int* src = eidx;
    const int* dst = eidx + N_EDGES;

    int* cnt  = (int*)d_ws;                         // [N]
    int* off  = cnt  + WS_STRIDE;                   // [N+1]
    int* cur  = off  + WS_STRIDE;                   // [N]
    int* bsum = cur  + WS_STRIDE;                   // [512]
    int* csr  = bsum + 512;                         // [E]
    unsigned short* wb = (unsigned short*)(csr + N_EDGES);   // [128*128]
    unsigned short* hb = wb + (size_t)DIM * DIM;             // [N*128] bf16

    // xb lives in d_out's first half (25.6 MB of 51.2 MB); fully overwritten
    // by gcn_mfma's final output write each call -> deterministic.
    unsigned short* xb = (unsigned short*)d_out;

    hipMemsetAsync(cnt, 0, (size_t)N_NODES * sizeof(int), stream);

    gcn_xconv<<<N_NODES * DIM / (256 * 8), 256, 0, stream>>>(x, (unsigned int*)xb);
    gcn_wconv<<<DIM * DIM / 256, 256, 0, stream>>>(W, wb);
    gcn_hist <<<(N_EDGES + 255) / 256, 256, 0, stream>>>(dst, cnt);
    gcn_scan1<<<N_CHUNKS, 256, 0, stream>>>(cnt, off, bsum);
    gcn_scan2<<<1, 128, 0, stream>>>(bsum);
    gcn_scan3<<<N_CHUNKS, 256, 0, stream>>>(off, cur, bsum);
    gcn_fill <<<(N_EDGES + 255) / 256, 256, 0, stream>>>(src, dst, cur, csr);
    gcn_gather<<<N_NODES / 16, 256, 0, stream>>>(xb, off, csr, (unsigned int*)hb);
    gcn_mfma <<<(N_TILES + 3) / 4, 256, 0, stream>>>(
        (const short*)hb, (const short*)wb, bias, out);
}

// Round 5
// 148.633 us; speedup vs baseline: 8.9928x; 1.0860x over previous
//
#include <hip/hip_runtime.h>
#include <hip/hip_bf16.h>

constexpr int N_NODES = 100000;
constexpr int DIM     = 128;
constexpr int N_EDGES = 640000;

constexpr int SCAN_CHUNK  = 1024;
constexpr int N_CHUNKS    = (N_NODES + SCAN_CHUNK - 1) / SCAN_CHUNK;   // 98
constexpr int WS_STRIDE   = 100352;                                    // ints

constexpr int XCONV_XBLOCKS = N_NODES * DIM / (256 * 8);               // 6250
constexpr int XCONV_WBLOCKS = DIM * DIM / (256 * 8);                   // 8

typedef __attribute__((ext_vector_type(4))) float        f32x4;
typedef __attribute__((ext_vector_type(8))) short        bf16x8;
typedef __attribute__((ext_vector_type(4))) unsigned int u32x4;

static __device__ inline unsigned short f2bf(float f) {
    __hip_bfloat16 h = __float2bfloat16(f);   // RNE
    return *reinterpret_cast<unsigned short*>(&h);
}
static __device__ inline float bf_lo(unsigned u) { return __uint_as_float(u << 16); }
static __device__ inline float bf_hi(unsigned u) { return __uint_as_float(u & 0xffff0000u); }

// ---------------------------------------------------------------------------
// 1) Fused: x->bf16 (blocks < 6250), W->bf16 (blocks >= 6250), zero cnt.
//    Stream order makes cnt=0 visible to gcn_hist.
// ---------------------------------------------------------------------------
__global__ __launch_bounds__(256) void gcn_conv(const float* __restrict__ x,
                                                const float* __restrict__ W,
                                                unsigned int* __restrict__ xb,
                                                unsigned int* __restrict__ wb,
                                                int* __restrict__ cnt)
{
    const int b   = blockIdx.x;
    const int gid = b * 256 + threadIdx.x;

    if (gid < N_NODES) cnt[gid] = 0;

    const float*  src;
    unsigned int* dst;
    int i;
    if (b < XCONV_XBLOCKS) {
        src = x;  dst = xb;  i = gid;
    } else {
        src = W;  dst = wb;  i = gid - XCONV_XBLOCKS * 256;
    }
    const f32x4* s4 = reinterpret_cast<const f32x4*>(src);
    f32x4 a = s4[2 * i];
    f32x4 c = s4[2 * i + 1];
    u32x4 o;
    o.x = (unsigned)f2bf(a.x) | ((unsigned)f2bf(a.y) << 16);
    o.y = (unsigned)f2bf(a.z) | ((unsigned)f2bf(a.w) << 16);
    o.z = (unsigned)f2bf(c.x) | ((unsigned)f2bf(c.y) << 16);
    o.w = (unsigned)f2bf(c.z) | ((unsigned)f2bf(c.w) << 16);
    reinterpret_cast<u32x4*>(dst)[i] = o;
}

// ---------------------------------------------------------------------------
// 2) Histogram of dst -> cnt[n]
// ---------------------------------------------------------------------------
__global__ __launch_bounds__(256) void gcn_hist(const int* __restrict__ dst,
                                                int* __restrict__ cnt)
{
    int e = blockIdx.x * 256 + threadIdx.x;
    if (e < N_EDGES) atomicAdd(&cnt[dst[e]], 1);
}

// ---------------------------------------------------------------------------
// 3) Exclusive scan of cnt -> off (3 kernels)
// ---------------------------------------------------------------------------
__global__ __launch_bounds__(256) void gcn_scan1(const int* __restrict__ cnt,
                                                 int* __restrict__ off,
                                                 int* __restrict__ bsum)
{
    __shared__ int s[256];
    const int t    = threadIdx.x;
    const int base = blockIdx.x * SCAN_CHUNK + t * 4;

    int v0 = (base + 0 < N_NODES) ? cnt[base + 0] : 0;
    int v1 = (base + 1 < N_NODES) ? cnt[base + 1] : 0;
    int v2 = (base + 2 < N_NODES) ? cnt[base + 2] : 0;
    int v3 = (base + 3 < N_NODES) ? cnt[base + 3] : 0;

    s[t] = v0 + v1 + v2 + v3;
    __syncthreads();
    for (int d = 1; d < 256; d <<= 1) {
        int add = (t >= d) ? s[t - d] : 0;
        __syncthreads();
        s[t] += add;
        __syncthreads();
    }
    int excl = (t > 0) ? s[t - 1] : 0;

    if (base + 0 < N_NODES) off[base + 0] = excl;
    if (base + 1 < N_NODES) off[base + 1] = excl + v0;
    if (base + 2 < N_NODES) off[base + 2] = excl + v0 + v1;
    if (base + 3 < N_NODES) off[base + 3] = excl + v0 + v1 + v2;
    if (t == 255) bsum[blockIdx.x] = s[255];
}

__global__ __launch_bounds__(128) void gcn_scan2(int* __restrict__ bsum)
{
    __shared__ int s[128];
    const int t = threadIdx.x;
    s[t] = (t < N_CHUNKS) ? bsum[t] : 0;
    __syncthreads();
    for (int d = 1; d < 128; d <<= 1) {
        int add = (t >= d) ? s[t - d] : 0;
        __syncthreads();
        s[t] += add;
        __syncthreads();
    }
    if (t < N_CHUNKS) bsum[t] = (t > 0) ? s[t - 1] : 0;
}

__global__ __launch_bounds__(256) void gcn_scan3(int* __restrict__ off,
                                                 const int* __restrict__ bsum)
{
    const int t    = threadIdx.x;
    const int base = blockIdx.x * SCAN_CHUNK + t * 4;
    const int add  = bsum[blockIdx.x];
    #pragma unroll
    for (int q = 0; q < 4; ++q) {
        int idx = base + q;
        if (idx < N_NODES) off[idx] += add;
    }
}

// ---------------------------------------------------------------------------
// 4) Fill CSR, bumping off[] itself. Post-condition: off[n] == old_off[n+1],
//    so node n's slice is [ n ? off[n-1] : 0 , off[n] ).
// ---------------------------------------------------------------------------
__global__ __launch_bounds__(256) void gcn_fill(const int* __restrict__ src,
                                                const int* __restrict__ dst,
                                                int* __restrict__ off,
                                                int* __restrict__ csr)
{
    int e = blockIdx.x * 256 + threadIdx.x;
    if (e < N_EDGES) {
        int d = dst[e];
        int p = atomicAdd(&off[d], 1);
        csr[p] = src[e];
    }
}

// ---------------------------------------------------------------------------
// 5) Gather-aggregate from bf16 x: h[n] = sum(xb[src])/max(deg,1) + xb[n]
//    16 lanes per node, 16B per lane, 4-deep edge unroll for MLP.
// ---------------------------------------------------------------------------
static __device__ inline void acc8(float* acc, u32x4 v) {
    #pragma unroll
    for (int q = 0; q < 4; ++q) {
        unsigned u = v[q];
        acc[2 * q]     += bf_lo(u);
        acc[2 * q + 1] += bf_hi(u);
    }
}

__global__ __launch_bounds__(256) void gcn_gather(
    const unsigned short* __restrict__ xb,
    const int* __restrict__ off,
    const int* __restrict__ csr,
    unsigned int* __restrict__ hb)
{
    const int tid  = threadIdx.x;
    const int lane = tid & 15;                        // 8 dims per lane
    const int n    = blockIdx.x * 16 + (tid >> 4);    // grid exact

    const int start = (n > 0) ? off[n - 1] : 0;
    const int end   = off[n];
    const int col8  = lane * 8;

    float acc[8];
    #pragma unroll
    for (int q = 0; q < 8; ++q) acc[q] = 0.0f;

    int i = start;
    for (; i + 4 <= end; i += 4) {
        int s0 = csr[i], s1 = csr[i + 1], s2 = csr[i + 2], s3 = csr[i + 3];
        u32x4 v0 = *reinterpret_cast<const u32x4*>(xb + (size_t)s0 * DIM + col8);
        u32x4 v1 = *reinterpret_cast<const u32x4*>(xb + (size_t)s1 * DIM + col8);
        u32x4 v2 = *reinterpret_cast<const u32x4*>(xb + (size_t)s2 * DIM + col8);
        u32x4 v3 = *reinterpret_cast<const u32x4*>(xb + (size_t)s3 * DIM + col8);
        acc8(acc, v0); acc8(acc, v1); acc8(acc, v2); acc8(acc, v3);
    }
    for (; i < end; ++i) {
        int s = csr[i];
        u32x4 v = *reinterpret_cast<const u32x4*>(xb + (size_t)s * DIM + col8);
        acc8(acc, v);
    }

    const float inv = 1.0f / fmaxf((float)(end - start), 1.0f);
    const u32x4 xr = *reinterpret_cast<const u32x4*>(xb + (size_t)n * DIM + col8);

    u32x4 o;
    #pragma unroll
    for (int q = 0; q < 4; ++q) {
        float h0 = acc[2 * q]     * inv + bf_lo(xr[q]);
        float h1 = acc[2 * q + 1] * inv + bf_hi(xr[q]);
        o[q] = (unsigned)f2bf(h0) | ((unsigned)f2bf(h1) << 16);
    }
    reinterpret_cast<u32x4*>(hb)[(size_t)n * (DIM / 8) + lane] = o;
}

// ---------------------------------------------------------------------------
// 6) MFMA GEMM: out = relu(h @ W^T + b)   (verified layout, unchanged)
// ---------------------------------------------------------------------------
constexpr int N_TILES = N_NODES / 16;   // 6250

__global__ __launch_bounds__(256) void gcn_mfma(
    const short* __restrict__ hb,
    const short* __restrict__ wb,
    const float* __restrict__ bias,
    float* __restrict__ out)
{
    const int wid  = threadIdx.x >> 6;
    const int lane = threadIdx.x & 63;
    const int tile = blockIdx.x * 4 + wid;
    if (tile >= N_TILES) return;
    const int row0 = tile * 16;

    const int r = lane & 15;
    const int g = lane >> 4;

    bf16x8 wf[8][4];
    #pragma unroll
    for (int c = 0; c < 8; ++c)
        #pragma unroll
        for (int t = 0; t < 4; ++t)
            wf[c][t] = *reinterpret_cast<const bf16x8*>(
                wb + (16 * c + r) * DIM + 32 * t + 8 * g);

    bf16x8 af[4];
    #pragma unroll
    for (int t = 0; t < 4; ++t)
        af[t] = *reinterpret_cast<const bf16x8*>(
            hb + (size_t)(row0 + r) * DIM + 32 * t + 8 * g);

    f32x4 acc[8];
    #pragma unroll
    for (int c = 0; c < 8; ++c) acc[c] = {0.f, 0.f, 0.f, 0.f};

    #pragma unroll
    for (int t = 0; t < 4; ++t)
        #pragma unroll
        for (int c = 0; c < 8; ++c)
            acc[c] = __builtin_amdgcn_mfma_f32_16x16x32_bf16(af[t], wf[c][t], acc[c], 0, 0, 0);

    #pragma unroll
    for (int c = 0; c < 8; ++c) {
        const float bj = bias[16 * c + r];
        #pragma unroll
        for (int q = 0; q < 4; ++q)
            out[(size_t)(row0 + 4 * g + q) * DIM + 16 * c + r] =
                fmaxf(acc[c][q] + bj, 0.0f);
    }
}

// ---------------------------------------------------------------------------
extern "C" void kernel_launch(void* const* d_in, const int* in_sizes, int n_in,
                              void* d_out, int out_size, void* d_ws, size_t ws_size,
                              hipStream_t stream)
{
    const float* x    = (const float*)d_in[0];
    const int*   eidx = (const int*)d_in[1];
    const float* W    = (const float*)d_in[2];
    const float* bias = (const float*)d_in[3];
    float*       out  = (float*)d_out;

    const int* src = eidx;
    const int* dst = eidx + N_EDGES;

    int* cnt  = (int*)d_ws;                         // [N]
    int* off  = cnt  + WS_STRIDE;                   // [N]
    int* bsum = off  + WS_STRIDE;                   // [512]
    int* csr  = bsum + 512;                         // [E]
    unsigned short* wb = (unsigned short*)(csr + N_EDGES);   // [128*128]
    unsigned short* hb = wb + (size_t)DIM * DIM;             // [N*128] bf16

    // xb lives in d_out's first half; fully overwritten by gcn_mfma each call.
    unsigned short* xb = (unsigned short*)d_out;

    gcn_conv <<<XCONV_XBLOCKS + XCONV_WBLOCKS, 256, 0, stream>>>(
        x, W, (unsigned int*)xb, (unsigned int*)wb, cnt);
    gcn_hist <<<(N_EDGES + 255) / 256, 256, 0, stream>>>(dst, cnt);
    gcn_scan1<<<N_CHUNKS, 256, 0, stream>>>(cnt, off, bsum);
    gcn_scan2<<<1, 128, 0, stream>>>(bsum);
    gcn_scan3<<<N_CHUNKS, 256, 0, stream>>>(off, bsum);
    gcn_fill <<<(N_EDGES + 255) / 256, 256, 0, stream>>>(src, dst, off, csr);
    gcn_gather<<<N_NODES / 16, 256, 0, stream>>>(xb, off, csr, (unsigned int*)hb);
    gcn_mfma <<<(N_TILES + 3) / 4, 256, 0, stream>>>(
        (const short*)hb, (const short*)wb, bias, out);
}